// Round 2
// baseline (381.127 us; speedup 1.0000x reference)
//
#include <hip/hip_runtime.h>
#include <math.h>

// LSEP loss: loss = log1p( sum_rows (sum_{t==0} exp(x)) * (sum_{t>0} exp(-x)) ) / B
// R1: coalesced LDS-staged version. Staging threads load flat float4/int4
// (16 B/lane dense = the 6.3 TB/s pattern), compute exp during staging, and
// write per-float4 partial pair-sums (a,b) to LDS. Compute thread per row
// sums 6 partials each and accumulates a*b in f64.

constexpr int  ROWS  = 2000000;
constexpr int  BLOCK = 256;
constexpr int  GRID  = 2048;                      // 8 blocks/CU
constexpr int  TILE  = 256;                       // rows per tile
constexpr int  NT    = (ROWS + TILE - 1) / TILE;  // 7813 tiles (last partial)
constexpr long TOT4  = (long)ROWS * 6;            // 12,000,000 float4s

__global__ __launch_bounds__(BLOCK) void lsep_main(
        const float4* __restrict__ input,
        const int4*   __restrict__ target,
        double*       __restrict__ partials)
{
    __shared__ float  lds_a[TILE * 7];   // stride-7 pad: gcd(7,32)=1, conflict-free
    __shared__ float  lds_b[TILE * 7];
    __shared__ double sred[BLOCK / 64];

    const int t = threadIdx.x;
    double acc = 0.0;

    for (int tile = blockIdx.x; tile < NT; tile += GRID) {
        const long base4 = (long)tile * (TILE * 6);

        // ---- stage: issue all 12 coalesced loads first (memory ILP) ----
        float4 x[6]; int4 tg[6]; bool ok[6];
        #pragma unroll
        for (int k = 0; k < 6; ++k) {
            const long g4 = base4 + t + k * BLOCK;
            ok[k] = (g4 < TOT4);
            if (ok[k]) { x[k] = input[g4]; tg[k] = target[g4]; }
        }

        // ---- transform: 4 exps per float4, write partial pair to LDS ----
        #pragma unroll
        for (int k = 0; k < 6; ++k) {
            if (ok[k]) {
                float a = 0.0f, b = 0.0f, e;
                e = __expf(tg[k].x > 0 ? -x[k].x : x[k].x); if (tg[k].x > 0) b += e; else a += e;
                e = __expf(tg[k].y > 0 ? -x[k].y : x[k].y); if (tg[k].y > 0) b += e; else a += e;
                e = __expf(tg[k].z > 0 ? -x[k].z : x[k].z); if (tg[k].z > 0) b += e; else a += e;
                e = __expf(tg[k].w > 0 ? -x[k].w : x[k].w); if (tg[k].w > 0) b += e; else a += e;
                const int lr  = t + k * BLOCK;        // 0..1535 within tile
                const int row = lr / 6;               // const-div, magic mul
                const int j   = lr - row * 6;
                lds_a[row * 7 + j] = a;
                lds_b[row * 7 + j] = b;
            }
        }
        __syncthreads();

        // ---- per-row combine: s_neg * s_pos ----
        const long grow = (long)tile * TILE + t;
        if (grow < ROWS) {
            const int r7 = t * 7;
            const float sa = ((lds_a[r7+0] + lds_a[r7+1]) + (lds_a[r7+2] + lds_a[r7+3]))
                           +  (lds_a[r7+4] + lds_a[r7+5]);
            const float sb = ((lds_b[r7+0] + lds_b[r7+1]) + (lds_b[r7+2] + lds_b[r7+3]))
                           +  (lds_b[r7+4] + lds_b[r7+5]);
            acc += (double)sa * (double)sb;
        }
        __syncthreads();   // protect LDS before next tile's stores
    }

    // ---- block reduction (f64) ----
    #pragma unroll
    for (int off = 32; off > 0; off >>= 1)
        acc += __shfl_down(acc, off, 64);
    if ((t & 63) == 0) sred[t >> 6] = acc;
    __syncthreads();
    if (t == 0)
        partials[blockIdx.x] = (sred[0] + sred[1]) + (sred[2] + sred[3]);
}

__global__ void lsep_finalize(const double* __restrict__ partials,
                              float* __restrict__ out)
{
    __shared__ double sred[4];
    const int t = threadIdx.x;
    double s = 0.0;
    #pragma unroll
    for (int i = 0; i < GRID / 256; ++i) s += partials[t + i * 256];
    #pragma unroll
    for (int off = 32; off > 0; off >>= 1)
        s += __shfl_down(s, off, 64);
    if ((t & 63) == 0) sred[t >> 6] = s;
    __syncthreads();
    if (t == 0)
        out[0] = (float)(log1p((sred[0] + sred[1]) + (sred[2] + sred[3])) / (double)ROWS);
}

extern "C" void kernel_launch(void* const* d_in, const int* in_sizes, int n_in,
                              void* d_out, int out_size, void* d_ws, size_t ws_size,
                              hipStream_t stream) {
    const float4* input  = (const float4*)d_in[0];
    const int4*   target = (const int4*)d_in[1];
    double*       ws     = (double*)d_ws;    // GRID f64 partials (16 KB)
    float*        out    = (float*)d_out;

    lsep_main<<<GRID, BLOCK, 0, stream>>>(input, target, ws);
    lsep_finalize<<<1, 256, 0, stream>>>(ws, out);
}

// Round 3
// 377.398 us; speedup vs baseline: 1.0099x; 1.0099x over previous
//
#include <hip/hip_runtime.h>
#include <math.h>

// LSEP loss: loss = log1p( sum_rows (sum_{t==0} exp(x)) * (sum_{t>0} exp(-x)) ) / B
// R2: half-row per thread. Thread t owns half-row h (3 float4 + 3 int4,
// 48 B stride), combines with partner lane via __shfl_xor(1). No LDS, no
// barriers, no bounds checks; explicit rotating-buffer prefetch for memory ILP.

constexpr int  ROWS    = 2000000;
constexpr int  HALVES  = ROWS * 2;           // 4,000,000 half-rows
constexpr int  BLOCK   = 256;
constexpr int  GRID    = 3125;               // 3125*256 = 800000 threads
constexpr int  THREADS = GRID * BLOCK;
constexpr int  ITERS   = HALVES / THREADS;   // exactly 5

__global__ __launch_bounds__(BLOCK, 4) void lsep_main(
        const float4* __restrict__ input,
        const int4*   __restrict__ target,
        double*       __restrict__ partials)
{
    const int tid = blockIdx.x * BLOCK + threadIdx.x;

    double acc = 0.0;

    // current-iteration buffers
    float4 xa0, xa1, xa2; int4 ta0, ta1, ta2;
    {
        const int f = 3 * tid;
        xa0 = input[f];  xa1 = input[f + 1];  xa2 = input[f + 2];
        ta0 = target[f]; ta1 = target[f + 1]; ta2 = target[f + 2];
    }

    int h = tid;
    #pragma unroll
    for (int i = 0; i < ITERS; ++i) {
        // ---- prefetch next half-row (compile-time-uniform guard) ----
        float4 xb0, xb1, xb2; int4 tb0, tb1, tb2;
        if (i + 1 < ITERS) {
            const int f = 3 * (h + THREADS);
            xb0 = input[f];  xb1 = input[f + 1];  xb2 = input[f + 2];
            tb0 = target[f]; tb1 = target[f + 1]; tb2 = target[f + 2];
        }

        // ---- compute current: per-half-row (a,b) partial sums ----
        float a = 0.0f, b = 0.0f, e;
        #define LSEP_ELEM(xc, tc) \
            e = __expf(tc > 0 ? -xc : xc); \
            if (tc > 0) b += e; else a += e;
        LSEP_ELEM(xa0.x, ta0.x) LSEP_ELEM(xa0.y, ta0.y) LSEP_ELEM(xa0.z, ta0.z) LSEP_ELEM(xa0.w, ta0.w)
        LSEP_ELEM(xa1.x, ta1.x) LSEP_ELEM(xa1.y, ta1.y) LSEP_ELEM(xa1.z, ta1.z) LSEP_ELEM(xa1.w, ta1.w)
        LSEP_ELEM(xa2.x, ta2.x) LSEP_ELEM(xa2.y, ta2.y) LSEP_ELEM(xa2.z, ta2.z) LSEP_ELEM(xa2.w, ta2.w)
        #undef LSEP_ELEM

        // ---- combine the two halves of the row (lanes 2k, 2k+1) ----
        const float sa = a + __shfl_xor(a, 1, 64);
        const float sb = b + __shfl_xor(b, 1, 64);
        acc += (double)sa * (double)sb;   // each row counted twice; scaled later

        // rotate buffers
        xa0 = xb0; xa1 = xb1; xa2 = xb2;
        ta0 = tb0; ta1 = tb1; ta2 = tb2;
        h += THREADS;
    }

    // ---- block reduction (f64) ----
    __shared__ double sred[BLOCK / 64];
    #pragma unroll
    for (int off = 32; off > 0; off >>= 1)
        acc += __shfl_down(acc, off, 64);
    const int t = threadIdx.x;
    if ((t & 63) == 0) sred[t >> 6] = acc;
    __syncthreads();
    if (t == 0)
        partials[blockIdx.x] = (sred[0] + sred[1]) + (sred[2] + sred[3]);
}

__global__ void lsep_finalize(const double* __restrict__ partials,
                              float* __restrict__ out)
{
    __shared__ double sred[4];
    const int t = threadIdx.x;
    double s = 0.0;
    for (int i = t; i < GRID; i += 256) s += partials[i];
    #pragma unroll
    for (int off = 32; off > 0; off >>= 1)
        s += __shfl_down(s, off, 64);
    if ((t & 63) == 0) sred[t >> 6] = s;
    __syncthreads();
    if (t == 0) {
        const double total = ((sred[0] + sred[1]) + (sred[2] + sred[3])) * 0.5;
        out[0] = (float)(log1p(total) / (double)ROWS);
    }
}

extern "C" void kernel_launch(void* const* d_in, const int* in_sizes, int n_in,
                              void* d_out, int out_size, void* d_ws, size_t ws_size,
                              hipStream_t stream) {
    const float4* input  = (const float4*)d_in[0];
    const int4*   target = (const int4*)d_in[1];
    double*       ws     = (double*)d_ws;    // GRID f64 partials (25 KB)
    float*        out    = (float*)d_out;

    lsep_main<<<GRID, BLOCK, 0, stream>>>(input, target, ws);
    lsep_finalize<<<1, 256, 0, stream>>>(ws, out);
}